// Round 1
// baseline (157.473 us; speedup 1.0000x reference)
//
#include <hip/hip_runtime.h>
#include <hip/hip_bf16.h>

// Spalize: out0[k,c,h,w] = img[c,h,w] * (mask[h,w]==k); out1 = mask (as float).
// K=50, C=3, H=W=512. Output is 157 MB -> pure HBM-write-bound (~26us floor).
// One thread handles 4 consecutive pixels; all 150 stores are 16B/lane coalesced.

#define K  50
#define C  3
#define H  512
#define W  512
#define HW (H * W)          // 262144 pixels
#define PIX_PER_THREAD 4
#define NTHREADS (HW / PIX_PER_THREAD)  // 65536

__global__ __launch_bounds__(256) void spalize_kernel(
    const float* __restrict__ img,   // [C,H,W]
    const int*   __restrict__ mask,  // [H,W] int32
    float*       __restrict__ out)   // [K,C,H,W] then [H,W] mask-as-float
{
    const int tid = blockIdx.x * blockDim.x + threadIdx.x;  // 0..65535
    const int p = tid * PIX_PER_THREAD;                     // pixel index

    // Load mask for 4 pixels (16B coalesced)
    const int4 m = *reinterpret_cast<const int4*>(mask + p);

    // Mask pass-through output (second tuple element), as float
    float4 mf;
    mf.x = (float)m.x; mf.y = (float)m.y; mf.z = (float)m.z; mf.w = (float)m.w;
    *reinterpret_cast<float4*>(out + (size_t)K * C * HW + p) = mf;

    // Load img for 3 channels x 4 pixels (3 x 16B coalesced)
    const float4 a0 = *reinterpret_cast<const float4*>(img + 0 * HW + p);
    const float4 a1 = *reinterpret_cast<const float4*>(img + 1 * HW + p);
    const float4 a2 = *reinterpret_cast<const float4*>(img + 2 * HW + p);

    float* base = out + p;

#pragma unroll
    for (int k = 0; k < K; ++k) {
        float4 o0, o1, o2;
        o0.x = (m.x == k) ? a0.x : 0.0f;
        o0.y = (m.y == k) ? a0.y : 0.0f;
        o0.z = (m.z == k) ? a0.z : 0.0f;
        o0.w = (m.w == k) ? a0.w : 0.0f;

        o1.x = (m.x == k) ? a1.x : 0.0f;
        o1.y = (m.y == k) ? a1.y : 0.0f;
        o1.z = (m.z == k) ? a1.z : 0.0f;
        o1.w = (m.w == k) ? a1.w : 0.0f;

        o2.x = (m.x == k) ? a2.x : 0.0f;
        o2.y = (m.y == k) ? a2.y : 0.0f;
        o2.z = (m.z == k) ? a2.z : 0.0f;
        o2.w = (m.w == k) ? a2.w : 0.0f;

        *reinterpret_cast<float4*>(base + ((size_t)(k * C + 0)) * HW) = o0;
        *reinterpret_cast<float4*>(base + ((size_t)(k * C + 1)) * HW) = o1;
        *reinterpret_cast<float4*>(base + ((size_t)(k * C + 2)) * HW) = o2;
    }
}

extern "C" void kernel_launch(void* const* d_in, const int* in_sizes, int n_in,
                              void* d_out, int out_size, void* d_ws, size_t ws_size,
                              hipStream_t stream) {
    const float* img  = (const float*)d_in[0];
    const int*   mask = (const int*)d_in[1];
    float*       out  = (float*)d_out;

    const int block = 256;
    const int grid  = NTHREADS / block;  // 256 blocks
    spalize_kernel<<<grid, block, 0, stream>>>(img, mask, out);
}

// Round 2
// 157.114 us; speedup vs baseline: 1.0023x; 1.0023x over previous
//
#include <hip/hip_runtime.h>
#include <hip/hip_bf16.h>

// Spalize: out0[k,c,h,w] = img[c,h,w] * (mask[h,w]==k); out1 = mask (as float).
// K=50, C=3, H=W=512. 157 MB output -> HBM-write-bound, floor ~26us @6.3TB/s.
// R0 lesson: 256 blocks (1 wave/SIMD) choked store issue at ~1 TB/s.
// R1: split K across gridDim.y (10 groups x 5 planes) -> 2560 blocks, 10240
// waves, so store latency/backpressure is hidden by TLP. Img+mask (4 MB)
// re-read 10x but L2/L3-resident -> HBM fetch ~flat.

#define K  50
#define C  3
#define H  512
#define W  512
#define HW (H * W)          // 262144 pixels
#define PIX_PER_THREAD 4
#define NTHREADS (HW / PIX_PER_THREAD)  // 65536 threads per k-group
#define KG 5                 // k-planes per block (K/KG = 10 groups)

__global__ __launch_bounds__(256) void spalize_kernel(
    const float* __restrict__ img,   // [C,H,W]
    const int*   __restrict__ mask,  // [H,W] int32
    float*       __restrict__ out)   // [K,C,H,W] then [H,W] mask-as-float
{
    const int tid = blockIdx.x * blockDim.x + threadIdx.x;  // 0..65535
    const int p = tid * PIX_PER_THREAD;                     // pixel index
    const int k0 = blockIdx.y * KG;                         // first k-plane

    // Load mask for 4 pixels (16B coalesced; L2-hot after first group)
    const int4 m = *reinterpret_cast<const int4*>(mask + p);

    // Mask pass-through output (second tuple element), written by one k-group
    if (blockIdx.y == 0) {
        float4 mf;
        mf.x = (float)m.x; mf.y = (float)m.y; mf.z = (float)m.z; mf.w = (float)m.w;
        *reinterpret_cast<float4*>(out + (size_t)K * C * HW + p) = mf;
    }

    // Load img for 3 channels x 4 pixels (3 x 16B coalesced; L2-hot)
    const float4 a0 = *reinterpret_cast<const float4*>(img + 0 * HW + p);
    const float4 a1 = *reinterpret_cast<const float4*>(img + 1 * HW + p);
    const float4 a2 = *reinterpret_cast<const float4*>(img + 2 * HW + p);

    float* base = out + p + (size_t)k0 * C * HW;

#pragma unroll
    for (int kk = 0; kk < KG; ++kk) {
        const int k = k0 + kk;
        float4 o0, o1, o2;
        o0.x = (m.x == k) ? a0.x : 0.0f;
        o0.y = (m.y == k) ? a0.y : 0.0f;
        o0.z = (m.z == k) ? a0.z : 0.0f;
        o0.w = (m.w == k) ? a0.w : 0.0f;

        o1.x = (m.x == k) ? a1.x : 0.0f;
        o1.y = (m.y == k) ? a1.y : 0.0f;
        o1.z = (m.z == k) ? a1.z : 0.0f;
        o1.w = (m.w == k) ? a1.w : 0.0f;

        o2.x = (m.x == k) ? a2.x : 0.0f;
        o2.y = (m.y == k) ? a2.y : 0.0f;
        o2.z = (m.z == k) ? a2.z : 0.0f;
        o2.w = (m.w == k) ? a2.w : 0.0f;

        *reinterpret_cast<float4*>(base + ((size_t)(kk * C + 0)) * HW) = o0;
        *reinterpret_cast<float4*>(base + ((size_t)(kk * C + 1)) * HW) = o1;
        *reinterpret_cast<float4*>(base + ((size_t)(kk * C + 2)) * HW) = o2;
    }
}

extern "C" void kernel_launch(void* const* d_in, const int* in_sizes, int n_in,
                              void* d_out, int out_size, void* d_ws, size_t ws_size,
                              hipStream_t stream) {
    const float* img  = (const float*)d_in[0];
    const int*   mask = (const int*)d_in[1];
    float*       out  = (float*)d_out;

    const int block = 256;
    dim3 grid(NTHREADS / block, K / KG);  // 256 x 10 = 2560 blocks
    spalize_kernel<<<grid, block, 0, stream>>>(img, mask, out);
}

// Round 3
// 156.869 us; speedup vs baseline: 1.0038x; 1.0016x over previous
//
#include <hip/hip_runtime.h>
#include <hip/hip_bf16.h>

// Spalize: out0[k,c,h,w] = img[c,h,w] * (mask[h,w]==k); out1 = mask (as float).
// K=50, C=3, H=W=512. 157 MB output -> HBM-write-bound.
// R0/R1 lesson: dur_us window = harness poison fill (~94us, fixed) + kernel.
// Kernel was ~63us (2.5 TB/s): 15 strided write streams per wave scattered
// dirty lines across 157 MB -> DRAM row thrash. The poison fill itself does
// 6.7 TB/s with a linear sweep over the SAME buffer.
// R2: one thread per 4 consecutive OUTPUT floats -> chip-wide single linear
// write sweep, exactly the fill's pattern. Wave-uniform (k,c) plane (256
// consecutive outputs per wave, HW % 256 == 0); mask/img reads coalesced,
// L2-hot on re-read (HBM fetch ~4 MB regardless).

#define K  50
#define C  3
#define H  512
#define W  512
#define HW (H * W)                 // 262144
#define OUT0 (K * C * HW)          // 39,321,600 floats
#define OUT_TOTAL (OUT0 + HW)      // 39,583,744 floats
#define BLOCK 256

__global__ __launch_bounds__(BLOCK) void spalize_kernel(
    const float* __restrict__ img,   // [C,H,W]
    const int*   __restrict__ mask,  // [H,W] int32
    float*       __restrict__ out)   // [K,C,H,W] then [H,W] mask-as-float
{
    const int tid = blockIdx.x * BLOCK + threadIdx.x;
    const int f = tid * 4;           // flat output float index (fits in int)

    if (f < OUT0) {
        const int plane = f >> 18;          // f / HW  (wave-uniform)
        const int p     = f & (HW - 1);     // pixel index
        const int k     = (plane * 0x5556) >> 16;  // plane / 3 (plane < 150)
        const int c     = plane - k * 3;

        const int4   m = *reinterpret_cast<const int4*>(mask + p);
        const float4 a = *reinterpret_cast<const float4*>(img + c * HW + p);

        float4 o;
        o.x = (m.x == k) ? a.x : 0.0f;
        o.y = (m.y == k) ? a.y : 0.0f;
        o.z = (m.z == k) ? a.z : 0.0f;
        o.w = (m.w == k) ? a.w : 0.0f;
        *reinterpret_cast<float4*>(out + f) = o;
    } else {
        const int p = f - OUT0;             // mask pass-through
        const int4 m = *reinterpret_cast<const int4*>(mask + p);
        float4 mf;
        mf.x = (float)m.x; mf.y = (float)m.y;
        mf.z = (float)m.z; mf.w = (float)m.w;
        *reinterpret_cast<float4*>(out + f) = mf;
    }
}

extern "C" void kernel_launch(void* const* d_in, const int* in_sizes, int n_in,
                              void* d_out, int out_size, void* d_ws, size_t ws_size,
                              hipStream_t stream) {
    const float* img  = (const float*)d_in[0];
    const int*   mask = (const int*)d_in[1];
    float*       out  = (float*)d_out;

    const int nthreads = OUT_TOTAL / 4;          // 9,895,936
    const int grid = nthreads / BLOCK;           // 38,656 blocks (exact)
    spalize_kernel<<<grid, BLOCK, 0, stream>>>(img, mask, out);
}